// Round 18
// baseline (312.919 us; speedup 1.0000x reference)
//
#include <hip/hip_runtime.h>

typedef unsigned short u16;
typedef unsigned int u32;
typedef __attribute__((ext_vector_type(8))) __bf16 bf16x8;
typedef __attribute__((ext_vector_type(4))) float f32x4;
typedef __attribute__((ext_vector_type(4))) _Float16 f16x4;
typedef __attribute__((ext_vector_type(2))) unsigned u32x2;

constexpr int TT = 8, NN = 20000, DD = 128, EE = 320000;
constexpr int MAXDEG = 64;        // P(Poisson(16) > 64) ~ 1e-19; rounds 0-17 passed with cap
constexpr float SCL = 0.17677669529663687f;  // 1/sqrt(32)
constexpr int VBLK2 = 544;        // bytes per ch-tile block (512 data + 32 pad)
constexpr u32 SLAB = (u32)(NN * DD);  // u16 elements per K/V slab (fits u32 addressing)

__device__ __forceinline__ u16 f2bf(float f) {
  return __builtin_bit_cast(u16, (__bf16)f);
}
__device__ __forceinline__ u16 f2h(float f) {
  return __builtin_bit_cast(u16, (_Float16)f);
}
__device__ __forceinline__ float blo(u32 u) { return __uint_as_float(u << 16); }
__device__ __forceinline__ float bhi(u32 u) { return __uint_as_float(u & 0xffff0000u); }

__device__ __forceinline__ bf16x8 cvt8(float4 f0, float4 f1) {
  bf16x8 r;
  r[0] = (__bf16)f0.x; r[1] = (__bf16)f0.y; r[2] = (__bf16)f0.z; r[3] = (__bf16)f0.w;
  r[4] = (__bf16)f1.x; r[5] = (__bf16)f1.y; r[6] = (__bf16)f1.z; r[7] = (__bf16)f1.w;
  return r;
}

// -- init: zero cnt + pe_k + W->bf16 (SgT table removed; S read direct in agg) -
__global__ void k_init(const float* __restrict__ pe_table, const float* __restrict__ Wkpe,
                       const float* __restrict__ Wq, const float* __restrict__ Wkh,
                       const float* __restrict__ Wv,
                       float* __restrict__ pek, int* __restrict__ cnt,
                       u16* __restrict__ Wb) {
  int i = blockIdx.x * 256 + threadIdx.x;
  if (i < NN) cnt[i] = 0;
  if (i < 5 * DD) {
    int dt = i >> 7, j = i & 127;
    float s = 0.f;
    for (int p = 0; p < 8; ++p) s += pe_table[dt * 8 + p] * Wkpe[j * 8 + p];
    pek[i] = s;
  }
  if (i < 3 * DD * DD) {
    int y = i / (DD * DD), idx = i % (DD * DD);
    const float* W = (y == 0) ? Wq : (y == 1) ? Wkh : Wv;
    Wb[i] = f2bf(W[idx]);
  }
}

// ---------------- slot-CSR build (dst is t-invariant; fixed-stride slots) ------
__global__ void k_build(const int* __restrict__ src, const int* __restrict__ dst,
                        int* __restrict__ cnt, int* __restrict__ eslot) {
  int i = blockIdx.x * 256 + threadIdx.x;
  if (i < EE) {
    int d = dst[i];
    int p = atomicAdd(&cnt[d], 1);
    if (p < MAXDEG) eslot[d * MAXDEG + p] = src[i];
  }
}

// --- projection, OPERAND-SWAPPED (A=W rows, B=H rows): D row=channel col=token
// -> lane holds 4 consecutive channels of one token: ushort4 8-B stores.
__global__ __launch_bounds__(256) void k_proj8(
    const float* __restrict__ Hm, const u16* __restrict__ Wb,
    u16* __restrict__ Qb, u16* __restrict__ Kb, u16* __restrict__ Vb) {
  int tid = threadIdx.x;
  int lane = tid & 63, wv = tid >> 6;
  int wr = wv >> 1, wc = wv & 1;      // wr: channel-half (A=W), wc: token-half (B=H)
  int l15 = lane & 15, lq = lane >> 4;
  size_t m0 = (size_t)blockIdx.x * 128;

  // hoist H tile fragments ONCE (B-operand now; 16 x bf16x8 = 64 VGPR)
  bf16x8 b[4][4];
#pragma unroll
  for (int ks = 0; ks < 4; ++ks) {
    int col0 = ks * 32 + lq * 8;
#pragma unroll
    for (int j = 0; j < 4; ++j) {
      const float* gp = Hm + (m0 + wc * 64 + j * 16 + l15) * DD + col0;
      b[ks][j] = cvt8(*(const float4*)gp, *(const float4*)(gp + 4));
    }
  }

  for (int y = 0; y < 3; ++y) {
    u16* Out = (y == 0) ? Qb : (y == 1) ? Kb : Vb;
    const bool asF16 = (y == 2);
    const float postm = (y == 0) ? SCL : 1.f;
    const u16* Wy = Wb + y * DD * DD;

    f32x4 acc[4][4];
    for (int i = 0; i < 4; ++i)
      for (int j = 0; j < 4; ++j) acc[i][j] = (f32x4){0.f, 0.f, 0.f, 0.f};

    for (int ks = 0; ks < 4; ++ks) {
      int col0 = ks * 32 + lq * 8;
      bf16x8 a[4];
#pragma unroll
      for (int i = 0; i < 4; ++i)
        a[i] = *(const bf16x8*)(Wy + (wr * 64 + i * 16 + l15) * DD + col0);
#pragma unroll
      for (int i = 0; i < 4; ++i)
#pragma unroll
        for (int j = 0; j < 4; ++j)
          acc[i][j] = __builtin_amdgcn_mfma_f32_16x16x32_bf16(a[i], b[ks][j], acc[i][j], 0, 0, 0);
    }

    // store: token = wc*64 + j*16 + l15; channels = wr*64 + i*16 + lq*4 + (0..3)
#pragma unroll
    for (int i = 0; i < 4; ++i)
#pragma unroll
      for (int j = 0; j < 4; ++j) {
        size_t row = m0 + wc * 64 + j * 16 + l15;
        int ch = wr * 64 + i * 16 + lq * 4;
        float v0 = acc[i][j][0] * postm, v1 = acc[i][j][1] * postm;
        float v2 = acc[i][j][2] * postm, v3 = acc[i][j][3] * postm;
        ushort4 pk;
        if (asF16) {
          pk = make_ushort4(f2h(v0), f2h(v1), f2h(v2), f2h(v3));
        } else {
          pk = make_ushort4(f2bf(v0), f2bf(v1), f2bf(v2), f2bf(v3));
        }
        *(ushort4*)(Out + row * DD + ch) = pk;
      }
  }
}

// ------- MFMA aggregation: FLATTENED extended-key jobs (ext = tp*deg + key) ---
// offF[ext] = tp*SLAB + src*DD (u32); gateF[ext] = clamp(S)+1e-6 w/ tp in LSBs
// w[t][ext] = exp(sc + eW[tp][t]) * gate  (eW = -1e30 outside window -> w = 0)
__global__ __launch_bounds__(256, 8) void k_agg16(
    const u16* __restrict__ Qb, const u16* __restrict__ Kb, const u16* __restrict__ Vb,
    const float* __restrict__ Sarr, const float* __restrict__ pek,
    const float* __restrict__ relb,
    const int* __restrict__ cnt, const int* __restrict__ eslot,
    float* __restrict__ outp) {
  __shared__ u32 offF[TT * MAXDEG];     // flattened element offsets (pad = 0)
  __shared__ float gateF[TT * MAXDEG];  // flattened gates, tp stuffed in 3 LSBs
  __shared__ float eW[4][TT][16];       // per-head log-E, invalid = -1e30
  __shared__ u16 VldsS[4][VBLK2];       // per-wave V staging
  int tid = threadIdx.x;
  const int h = tid >> 6, lane = tid & 63;
  const int n = blockIdx.x;

  int deg = min(cnt[n], MAXDEG);
  const int extTot = deg * TT;
  for (int i = tid; i < TT * MAXDEG; i += 256) {
    u32 eoff = 0u, tp = 0u;
    float g = 0.f;
    if (i < extTot) {
      tp = (u32)i / (u32)deg;
      u32 key = (u32)i - tp * (u32)deg;
      int s = eslot[n * MAXDEG + (int)key];
      eoff = tp * SLAB + (u32)(s * DD);
      float raw = Sarr[(size_t)tp * NN + s];
      g = fminf(fmaxf(raw, 0.f), 1.f) + 1e-6f;
    }
    offF[i] = eoff;
    gateF[i] = __uint_as_float((__float_as_uint(g) & ~7u) | tp);
  }

  const int t16 = lane & 15, qo = lane >> 4, qo4 = qo * 4;
  const int h32 = h * 32;

  // Q^T B-fragment (prescaled by SCL in proj); zero rows t>=8
  uint4 qb;
  {
    bool qok = t16 < 8;
    const u16* Qp = Qb + ((size_t)(t16 & 7) * NN + n) * DD + h32 + qo * 8;
    qb = qok ? *(const uint4*)(Qp) : make_uint4(0u, 0u, 0u, 0u);
  }

  // eW: zero-fill own head's table (wave-internal, in-order DS), then lanes
  // (qo==0, t16<8) write L = (Qs . pe_dt) + relb[dt] at [tp = t16-dt][t16].
  {
    ((float*)&eW[h][0][0])[lane] = -1e30f;
    ((float*)&eW[h][0][0])[lane + 64] = -1e30f;
    float qf0 = blo(qb.x), qf1 = bhi(qb.x), qf2 = blo(qb.y), qf3 = bhi(qb.y);
    float qf4 = blo(qb.z), qf5 = bhi(qb.z), qf6 = blo(qb.w), qf7 = bhi(qb.w);
#pragma unroll
    for (int d = 0; d < 5; ++d) {
      const float* pp = pek + d * DD + h32 + qo * 8;
      float4 p0 = *(const float4*)pp;
      float4 p1 = *(const float4*)(pp + 4);
      float s = qf0 * p0.x + qf1 * p0.y + qf2 * p0.z + qf3 * p0.w
              + qf4 * p1.x + qf5 * p1.y + qf6 * p1.z + qf7 * p1.w;
      s += __shfl_xor(s, 16);
      s += __shfl_xor(s, 32);
      int tp = t16 - d;
      if (qo == 0 && t16 < 8 && tp >= 0) eW[h][tp][t16] = s + relb[d];
    }
  }
  __syncthreads();  // offF + gateF ready

  f32x4 num0 = (f32x4){0.f, 0.f, 0.f, 0.f};
  f32x4 num1 = (f32x4){0.f, 0.f, 0.f, 0.f};
  float dd = 0.f;

  if (deg > 0) {
    const int cmax = (extTot + 15) & ~15;
    const int nj = cmax >> 4;

    const int vkey = lane >> 2, vcb = lane & 3;
    u16* vbuf = &VldsS[h][0];
    unsigned trbase = (unsigned)(uintptr_t)vbuf + lane * 8;
    unsigned woff = (unsigned)((vcb >> 1) * VBLK2 + (vkey >> 2) * 128 +
                               (vkey & 3) * 32 + (vcb & 1) * 16);
    const float* eWh = (const float*)&eW[h][0][0];  // flat [tp*16 + t]
    const u32 kbase = (u32)(h32 + qo * 8);
    const u32 vbase = (u32)(h32 + vcb * 8);

    auto loadK = [&](int c) -> uint4 {
      u32 idx = offF[c + t16] + kbase;
      return *(const uint4*)(Kb + idx);
    };
    auto loadV = [&](int c) -> uint4 {
      u32 idx = offF[c + vkey] + vbase;
      return *(const uint4*)(Vb + idx);
    };
    auto writeV = [&](uint4 f) { *(uint4*)((char*)vbuf + woff) = f; };
    auto compute = [&](uint4 ka, int c) {
      f32x4 g4 = *(const f32x4*)&gateF[c + qo4];
      u32 tp0 = __float_as_uint(g4[0]) & 7u;
      u32 tp1 = __float_as_uint(g4[1]) & 7u;
      u32 tp2 = __float_as_uint(g4[2]) & 7u;
      u32 tp3 = __float_as_uint(g4[3]) & 7u;
      float Lf0 = eWh[tp0 * 16 + t16];
      float Lf1 = eWh[tp1 * 16 + t16];
      float Lf2 = eWh[tp2 * 16 + t16];
      float Lf3 = eWh[tp3 * 16 + t16];

      f32x4 z = (f32x4){0.f, 0.f, 0.f, 0.f};
      f32x4 sc = __builtin_amdgcn_mfma_f32_16x16x32_bf16(
          __builtin_bit_cast(bf16x8, ka), __builtin_bit_cast(bf16x8, qb), z, 0, 0, 0);

      float w0 = __expf(sc[0] + Lf0) * g4[0];
      float w1 = __expf(sc[1] + Lf1) * g4[1];
      float w2 = __expf(sc[2] + Lf2) * g4[2];
      float w3 = __expf(sc[3] + Lf3) * g4[3];
      dd += w0 + w1 + w2 + w3;
      u32x2 wpk;
      wpk.x = __builtin_bit_cast(u32, __builtin_amdgcn_cvt_pkrtz(w0, w1));
      wpk.y = __builtin_bit_cast(u32, __builtin_amdgcn_cvt_pkrtz(w2, w3));
      f16x4 wf = __builtin_bit_cast(f16x4, wpk);

      // PV B-fragments via HW transpose read (rule #18: waitcnt + sched_barrier)
      __builtin_amdgcn_sched_barrier(0);
      u32x2 vr0, vr1;
      asm volatile("ds_read_b64_tr_b16 %0, %1" : "=v"(vr0) : "v"(trbase));
      asm volatile("ds_read_b64_tr_b16 %0, %1 offset:544" : "=v"(vr1) : "v"(trbase));
      asm volatile("s_waitcnt lgkmcnt(0)");
      __builtin_amdgcn_sched_barrier(0);
      num0 = __builtin_amdgcn_mfma_f32_16x16x16f16(
          wf, __builtin_bit_cast(f16x4, vr0), num0, 0, 0, 0);
      num1 = __builtin_amdgcn_mfma_f32_16x16x16f16(
          wf, __builtin_bit_cast(f16x4, vr1), num1, 0, 0, 0);
    };

    // prologue: jobs 0 and 1 (2-deep prefetch), single linear counter
    uint4 kA = loadK(0);
    { uint4 v0 = loadV(0); writeV(v0); }
    uint4 kB = make_uint4(0u, 0u, 0u, 0u), vB = make_uint4(0u, 0u, 0u, 0u);
    if (nj > 1) { kB = loadK(16); vB = loadV(16); }
    int c0 = 0, c1 = 16, cn = 32;

    for (int j = 0; j < nj; ++j) {
      uint4 kC = make_uint4(0u, 0u, 0u, 0u), vC = make_uint4(0u, 0u, 0u, 0u);
      if (cn < cmax) { kC = loadK(cn); vC = loadV(cn); }
      compute(kA, c0);
      __builtin_amdgcn_sched_barrier(0);
      if (c1 < cmax) writeV(vB);
      kA = kB; kB = kC; vB = vC;
      c0 = c1; c1 = cn; cn += 16;
    }
  }

  // finalize: complete denominator, divide, write (head-disjoint channels)
  float Dh = dd;
  Dh += __shfl_xor(Dh, 16);
  Dh += __shfl_xor(Dh, 32);
#pragma unroll
  for (int r = 0; r < 4; ++r) {
    int t = qo4 + r;
    float Dt = __shfl(Dh, t);
    if (t < 8) {
      float inv = 1.f / fmaxf(Dt, 1e-12f);
      float* op = outp + ((size_t)t * NN + n) * DD + h32;
      op[t16] = num0[r] * inv;
      op[16 + t16] = num1[r] * inv;
    }
  }
}

// ---------------- host ----------------
extern "C" void kernel_launch(void* const* d_in, const int* in_sizes, int n_in,
                              void* d_out, int out_size, void* d_ws, size_t ws_size,
                              hipStream_t stream) {
  const float* Hm = (const float*)d_in[0];
  const float* S = (const float*)d_in[1];
  const float* Wq = (const float*)d_in[2];
  const float* Wkh = (const float*)d_in[3];
  const float* Wkpe = (const float*)d_in[4];
  const float* Wv = (const float*)d_in[5];
  const float* pe_table = (const float*)d_in[6];
  const float* relb = (const float*)d_in[7];
  const int* src = (const int*)d_in[8];
  const int* dst = (const int*)d_in[9];
  float* out = (float*)d_out;

  auto aup = [](size_t x) { return (x + 255) & ~(size_t)255; };
  char* base = (char*)d_ws;
  size_t off = 0;
  u16* Qb = (u16*)(base + off); off = aup(off + (size_t)TT * NN * DD * 2);
  u16* Kb = (u16*)(base + off); off = aup(off + (size_t)TT * NN * DD * 2);
  u16* Vb = (u16*)(base + off); off = aup(off + (size_t)TT * NN * DD * 2);
  float* pek = (float*)(base + off); off = aup(off + (size_t)5 * DD * 4);
  int* cnt = (int*)(base + off); off = aup(off + (size_t)NN * 4);
  int* eslot = (int*)(base + off); off = aup(off + (size_t)NN * MAXDEG * 4);
  u16* Wb = (u16*)(base + off); off = aup(off + (size_t)3 * DD * DD * 2);
  (void)ws_size; (void)in_sizes; (void)n_in; (void)out_size;

  k_init<<<(3 * DD * DD + 255) / 256, 256, 0, stream>>>(pe_table, Wkpe, Wq, Wkh, Wv,
                                                        pek, cnt, Wb);
  k_build<<<(EE + 255) / 256, 256, 0, stream>>>(src, dst, cnt, eslot);
  k_proj8<<<1250, 256, 0, stream>>>(Hm, Wb, Qb, Kb, Vb);
  k_agg16<<<NN, 256, 0, stream>>>(Qb, Kb, Vb, S, pek, relb, cnt, eslot, out);
}

// Round 19
// 299.933 us; speedup vs baseline: 1.0433x; 1.0433x over previous
//
#include <hip/hip_runtime.h>

typedef unsigned short u16;
typedef unsigned int u32;
typedef __attribute__((ext_vector_type(8))) __bf16 bf16x8;
typedef __attribute__((ext_vector_type(4))) float f32x4;
typedef __attribute__((ext_vector_type(4))) _Float16 f16x4;
typedef __attribute__((ext_vector_type(2))) unsigned u32x2;

constexpr int TT = 8, NN = 20000, DD = 128, EE = 320000;
constexpr int MAXDEG = 64;        // P(Poisson(16) > 64) ~ 1e-19; rounds 0-18 passed with cap
constexpr float SCL = 0.17677669529663687f;  // 1/sqrt(32)
constexpr int VBLK2 = 544;        // bytes per ch-tile block (512 data + 32 pad)
constexpr u32 SLAB = (u32)(NN * DD);  // u16 elements per K/V slab (fits u32 addressing)

__device__ __forceinline__ u16 f2bf(float f) {
  return __builtin_bit_cast(u16, (__bf16)f);
}
__device__ __forceinline__ u16 f2h(float f) {
  return __builtin_bit_cast(u16, (_Float16)f);
}
__device__ __forceinline__ float blo(u32 u) { return __uint_as_float(u << 16); }
__device__ __forceinline__ float bhi(u32 u) { return __uint_as_float(u & 0xffff0000u); }

__device__ __forceinline__ bf16x8 cvt8(float4 f0, float4 f1) {
  bf16x8 r;
  r[0] = (__bf16)f0.x; r[1] = (__bf16)f0.y; r[2] = (__bf16)f0.z; r[3] = (__bf16)f0.w;
  r[4] = (__bf16)f1.x; r[5] = (__bf16)f1.y; r[6] = (__bf16)f1.z; r[7] = (__bf16)f1.w;
  return r;
}

// -- init: zero cnt + pe_k + W->bf16 + clamped gate table SgT = clip(S)+1e-6 ---
__global__ void k_init(const float* __restrict__ pe_table, const float* __restrict__ Wkpe,
                       const float* __restrict__ Wq, const float* __restrict__ Wkh,
                       const float* __restrict__ Wv, const float* __restrict__ S,
                       float* __restrict__ pek, int* __restrict__ cnt,
                       u16* __restrict__ Wb, float* __restrict__ SgT) {
  int i = blockIdx.x * 256 + threadIdx.x;
  if (i < NN) cnt[i] = 0;
  if (i < 5 * DD) {
    int dt = i >> 7, j = i & 127;
    float s = 0.f;
    for (int p = 0; p < 8; ++p) s += pe_table[dt * 8 + p] * Wkpe[j * 8 + p];
    pek[i] = s;
  }
  if (i < 3 * DD * DD) {
    int y = i / (DD * DD), idx = i % (DD * DD);
    const float* W = (y == 0) ? Wq : (y == 1) ? Wkh : Wv;
    Wb[i] = f2bf(W[idx]);
  }
  if (i < TT * NN) {
    SgT[i] = fminf(fmaxf(S[i], 0.f), 1.f) + 1e-6f;
  }
}

// ---------------- slot-CSR build (dst is t-invariant; fixed-stride slots) ------
__global__ void k_build(const int* __restrict__ src, const int* __restrict__ dst,
                        int* __restrict__ cnt, int* __restrict__ eslot) {
  int i = blockIdx.x * 256 + threadIdx.x;
  if (i < EE) {
    int d = dst[i];
    int p = atomicAdd(&cnt[d], 1);
    if (p < MAXDEG) eslot[d * MAXDEG + p] = src[i];
  }
}

// --- LDS-free projection; A-frags hoisted; Q PRE-SCALED by SCL ---------------
__global__ __launch_bounds__(256) void k_proj6(
    const float* __restrict__ Hm, const u16* __restrict__ Wb,
    u16* __restrict__ Qb, u16* __restrict__ Kb, u16* __restrict__ Vb) {
  int tid = threadIdx.x;
  int lane = tid & 63, wv = tid >> 6;
  int wr = wv >> 1, wc = wv & 1;
  int l15 = lane & 15, lq = lane >> 4;
  size_t m0 = (size_t)blockIdx.x * 128;

  // load H tile fragments ONCE (16 x bf16x8 = 64 VGPR)
  bf16x8 a[4][4];
#pragma unroll
  for (int ks = 0; ks < 4; ++ks) {
    int col0 = ks * 32 + lq * 8;
#pragma unroll
    for (int i = 0; i < 4; ++i) {
      const float* gp = Hm + (m0 + wr * 64 + i * 16 + l15) * DD + col0;
      a[ks][i] = cvt8(*(const float4*)gp, *(const float4*)(gp + 4));
    }
  }

  for (int y = 0; y < 3; ++y) {
    u16* Out = (y == 0) ? Qb : (y == 1) ? Kb : Vb;
    const bool asF16 = (y == 2);
    const float postm = (y == 0) ? SCL : 1.f;
    const u16* Wy = Wb + y * DD * DD;

    f32x4 acc[4][4];
    for (int i = 0; i < 4; ++i)
      for (int j = 0; j < 4; ++j) acc[i][j] = (f32x4){0.f, 0.f, 0.f, 0.f};

    for (int ks = 0; ks < 4; ++ks) {
      int col0 = ks * 32 + lq * 8;
      bf16x8 b[4];
#pragma unroll
      for (int j = 0; j < 4; ++j)
        b[j] = *(const bf16x8*)(Wy + (wc * 64 + j * 16 + l15) * DD + col0);
#pragma unroll
      for (int i = 0; i < 4; ++i)
#pragma unroll
        for (int j = 0; j < 4; ++j)
          acc[i][j] = __builtin_amdgcn_mfma_f32_16x16x32_bf16(a[ks][i], b[j], acc[i][j], 0, 0, 0);
    }

#pragma unroll
    for (int i = 0; i < 4; ++i)
#pragma unroll
      for (int j = 0; j < 4; ++j)
#pragma unroll
        for (int g = 0; g < 4; ++g) {
          size_t row = m0 + wr * 64 + i * 16 + lq * 4 + g;
          int col = wc * 64 + j * 16 + l15;
          float v = acc[i][j][g] * postm;
          Out[row * DD + col] = asF16 ? f2h(v) : f2bf(v);
        }
  }
}

// ------- MFMA aggregation: u32 saddr-form gathers + cvt_pkrtz w-pack ----------
// gateS[8][64]: zero-padded gates; eW[h][8][16]: log-E (invalid = -1e30)
__global__ __launch_bounds__(256, 8) void k_agg14(
    const u16* __restrict__ Qb, const u16* __restrict__ Kb, const u16* __restrict__ Vb,
    const float* __restrict__ SgT, const float* __restrict__ pek,
    const float* __restrict__ relb,
    const int* __restrict__ cnt, const int* __restrict__ eslot,
    float* __restrict__ outp) {
  __shared__ int srcB[MAXDEG];          // premultiplied src*DD
  __shared__ float gateS[TT][MAXDEG];   // zero-padded
  __shared__ float eW[4][TT][16];       // per-head log-E, padded
  __shared__ u16 VldsS[4][VBLK2];       // per-wave V staging
  int tid = threadIdx.x;
  const int h = tid >> 6, lane = tid & 63;
  const int n = blockIdx.x;

  int deg = min(cnt[n], MAXDEG);
  if (tid < MAXDEG) {
    int s = (tid < deg) ? eslot[n * MAXDEG + tid] : 0;
    srcB[tid] = s * DD;
  }
  for (int i = tid; i < TT * MAXDEG; i += 256) {
    int tp = i >> 6, e = i & 63;
    float g = 0.f;
    if (e < deg) g = SgT[(size_t)tp * NN + eslot[n * MAXDEG + e]];
    gateS[tp][e] = g;
  }

  const int t16 = lane & 15, qo = lane >> 4, qo4 = qo * 4;
  const int h32 = h * 32;

  // Q^T B-fragment (prescaled by SCL in proj); zero rows t>=8
  uint4 qb;
  {
    bool qok = t16 < 8;
    const u16* Qp = Qb + ((size_t)(t16 & 7) * NN + n) * DD + h32 + qo * 8;
    qb = qok ? *(const uint4*)(Qp) : make_uint4(0u, 0u, 0u, 0u);
  }

  // eW: zero-fill own head's table (wave-internal, in-order DS), then lanes
  // (qo==0, t16<8) write L = (Qs . pe_dt) + relb[dt] at [tp = t16-dt][t16].
  {
    ((float*)&eW[h][0][0])[lane] = -1e30f;
    ((float*)&eW[h][0][0])[lane + 64] = -1e30f;
    float qf0 = blo(qb.x), qf1 = bhi(qb.x), qf2 = blo(qb.y), qf3 = bhi(qb.y);
    float qf4 = blo(qb.z), qf5 = bhi(qb.z), qf6 = blo(qb.w), qf7 = bhi(qb.w);
#pragma unroll
    for (int d = 0; d < 5; ++d) {
      const float* pp = pek + d * DD + h32 + qo * 8;
      float4 p0 = *(const float4*)pp;
      float4 p1 = *(const float4*)(pp + 4);
      float s = qf0 * p0.x + qf1 * p0.y + qf2 * p0.z + qf3 * p0.w
              + qf4 * p1.x + qf5 * p1.y + qf6 * p1.z + qf7 * p1.w;
      s += __shfl_xor(s, 16);
      s += __shfl_xor(s, 32);
      int tp = t16 - d;
      if (qo == 0 && t16 < 8 && tp >= 0) eW[h][tp][t16] = s + relb[d];
    }
  }
  __syncthreads();  // srcB + gateS ready

  f32x4 num0 = (f32x4){0.f, 0.f, 0.f, 0.f};
  f32x4 num1 = (f32x4){0.f, 0.f, 0.f, 0.f};
  float dd = 0.f;

  if (deg > 0) {
    const int degm1 = deg - 1;
    const int nch = (deg + 15) >> 4;
    const int cmax = nch << 4;
    const int nj = nch * 8;   // always >= 8

    const int vkey = lane >> 2, vcb = lane & 3;
    u16* vbuf = &VldsS[h][0];
    unsigned trbase = (unsigned)(uintptr_t)vbuf + lane * 8;
    unsigned woff = (unsigned)((vcb >> 1) * VBLK2 + (vkey >> 2) * 128 +
                               (vkey & 3) * 32 + (vcb & 1) * 16);
    const float* eWt = &eW[h][0][t16];
    const u32 kbase = (u32)(h32 + qo * 8);   // u32 element offsets -> saddr form
    const u32 vbase = (u32)(h32 + vcb * 8);

    auto loadK = [&](u32 koff, int c16) -> uint4 {
      u32 idx = koff + (u32)srcB[min(c16 + t16, degm1)] + kbase;
      return *(const uint4*)(Kb + idx);
    };
    auto loadV = [&](u32 koff, int c16) -> uint4 {
      u32 idx = koff + (u32)srcB[min(c16 + vkey, degm1)] + vbase;
      return *(const uint4*)(Vb + idx);
    };
    auto writeV = [&](uint4 f) { *(uint4*)((char*)vbuf + woff) = f; };
    auto compute = [&](uint4 ka, int tp, int c16) {
      float Lf = eWt[tp * 16];
      f32x4 g4 = *(const f32x4*)&gateS[tp][c16 + qo4];

      f32x4 z = (f32x4){0.f, 0.f, 0.f, 0.f};
      f32x4 sc = __builtin_amdgcn_mfma_f32_16x16x32_bf16(
          __builtin_bit_cast(bf16x8, ka), __builtin_bit_cast(bf16x8, qb), z, 0, 0, 0);

      float w0 = __expf(sc[0] + Lf) * g4[0];
      float w1 = __expf(sc[1] + Lf) * g4[1];
      float w2 = __expf(sc[2] + Lf) * g4[2];
      float w3 = __expf(sc[3] + Lf) * g4[3];
      dd += w0 + w1 + w2 + w3;
      u32x2 wpk;
      wpk.x = __builtin_bit_cast(u32, __builtin_amdgcn_cvt_pkrtz(w0, w1));
      wpk.y = __builtin_bit_cast(u32, __builtin_amdgcn_cvt_pkrtz(w2, w3));
      f16x4 wf = __builtin_bit_cast(f16x4, wpk);

      // PV B-fragments via HW transpose read (rule #18: waitcnt + sched_barrier)
      __builtin_amdgcn_sched_barrier(0);
      u32x2 vr0, vr1;
      asm volatile("ds_read_b64_tr_b16 %0, %1" : "=v"(vr0) : "v"(trbase));
      asm volatile("ds_read_b64_tr_b16 %0, %1 offset:544" : "=v"(vr1) : "v"(trbase));
      asm volatile("s_waitcnt lgkmcnt(0)");
      __builtin_amdgcn_sched_barrier(0);
      num0 = __builtin_amdgcn_mfma_f32_16x16x16f16(
          wf, __builtin_bit_cast(f16x4, vr0), num0, 0, 0, 0);
      num1 = __builtin_amdgcn_mfma_f32_16x16x16f16(
          wf, __builtin_bit_cast(f16x4, vr1), num1, 0, 0, 0);
    };

    // prologue: jobs 0 and 1 (nj >= 8 always)
    uint4 kA = loadK(0u, 0);
    { uint4 v0 = loadV(0u, 0); writeV(v0); }
    int tp0 = 0, c0 = 0;                          // job j (compute; V in LDS)
    int tp1 = 0, c1 = 16;
    u32 koff1 = 0u;
    if (c1 >= cmax) { c1 = 0; tp1 = 1; koff1 = SLAB; }
    uint4 kB = loadK(koff1, c1);                  // job j+1 (K,V in regs)
    uint4 vB = loadV(koff1, c1);
    int tpn = tp1, cn = c1;                       // job j+2 target
    u32 koffn = koff1;
    cn += 16; if (cn >= cmax) { cn = 0; ++tpn; koffn += SLAB; }

    for (int j = 0; j < nj; ++j) {
      bool more2 = (j + 2) < nj;
      uint4 kC = make_uint4(0u, 0u, 0u, 0u), vC = make_uint4(0u, 0u, 0u, 0u);
      if (more2) {
        kC = loadK(koffn, cn);
        vC = loadV(koffn, cn);
      }
      compute(kA, tp0, c0);
      __builtin_amdgcn_sched_barrier(0);
      if ((j + 1) < nj) writeV(vB);
      kA = kB; kB = kC; vB = vC;
      tp0 = tp1; c0 = c1;
      tp1 = tpn; c1 = cn;
      cn += 16; if (cn >= cmax) { cn = 0; ++tpn; koffn += SLAB; }
    }
  }

  // finalize: complete denominator, divide, write (head-disjoint channels)
  float Dh = dd;
  Dh += __shfl_xor(Dh, 16);
  Dh += __shfl_xor(Dh, 32);
#pragma unroll
  for (int r = 0; r < 4; ++r) {
    int t = qo4 + r;
    float Dt = __shfl(Dh, t);
    if (t < 8) {
      float inv = 1.f / fmaxf(Dt, 1e-12f);
      float* op = outp + ((size_t)t * NN + n) * DD + h32;
      op[t16] = num0[r] * inv;
      op[16 + t16] = num1[r] * inv;
    }
  }
}

// ---------------- host ----------------
extern "C" void kernel_launch(void* const* d_in, const int* in_sizes, int n_in,
                              void* d_out, int out_size, void* d_ws, size_t ws_size,
                              hipStream_t stream) {
  const float* Hm = (const float*)d_in[0];
  const float* S = (const float*)d_in[1];
  const float* Wq = (const float*)d_in[2];
  const float* Wkh = (const float*)d_in[3];
  const float* Wkpe = (const float*)d_in[4];
  const float* Wv = (const float*)d_in[5];
  const float* pe_table = (const float*)d_in[6];
  const float* relb = (const float*)d_in[7];
  const int* src = (const int*)d_in[8];
  const int* dst = (const int*)d_in[9];
  float* out = (float*)d_out;

  auto aup = [](size_t x) { return (x + 255) & ~(size_t)255; };
  char* base = (char*)d_ws;
  size_t off = 0;
  u16* Qb = (u16*)(base + off); off = aup(off + (size_t)TT * NN * DD * 2);
  u16* Kb = (u16*)(base + off); off = aup(off + (size_t)TT * NN * DD * 2);
  u16* Vb = (u16*)(base + off); off = aup(off + (size_t)TT * NN * DD * 2);
  float* pek = (float*)(base + off); off = aup(off + (size_t)5 * DD * 4);
  float* SgT = (float*)(base + off); off = aup(off + (size_t)TT * NN * 4);
  int* cnt = (int*)(base + off); off = aup(off + (size_t)NN * 4);
  int* eslot = (int*)(base + off); off = aup(off + (size_t)NN * MAXDEG * 4);
  u16* Wb = (u16*)(base + off); off = aup(off + (size_t)3 * DD * DD * 2);
  (void)ws_size; (void)in_sizes; (void)n_in; (void)out_size;

  k_init<<<(TT * NN + 255) / 256, 256, 0, stream>>>(pe_table, Wkpe, Wq, Wkh, Wv, S,
                                                    pek, cnt, Wb, SgT);
  k_build<<<(EE + 255) / 256, 256, 0, stream>>>(src, dst, cnt, eslot);
  k_proj6<<<1250, 256, 0, stream>>>(Hm, Wb, Qb, Kb, Vb);
  k_agg14<<<NN, 256, 0, stream>>>(Qb, Kb, Vb, SgT, pek, relb, cnt, eslot, out);
}